// Round 7
// baseline (52.794 us; speedup 1.0000x reference)
//
#include <hip/hip_runtime.h>
#include <hip/hip_cooperative_groups.h>
#include <math.h>

namespace cg = cooperative_groups;

#define TPB    256
#define NBLK   32
#define PERCAP 256        // candidate slots per block region in d_ws
#define CAPS   4096       // solve-phase LDS candidate capacity
#define NW     (TPB / 64)

typedef unsigned long long ull;

__device__ __forceinline__ ull umin64(ull a, ull b) { return a < b ? a : b; }
__device__ __forceinline__ ull umax64(ull a, ull b) { return a > b ? a : b; }

// Branchless order-statistic merge of two ascending 5-lists of 64-bit keys.
// Key = (dist_bits << 32) | p. obs_idx is sorted, so ordering/tie-break by
// cell index p is a monotone bijection of the reference's obs-enumeration
// index j -> exact jax.lax.top_k semantics (lower index wins ties).
__device__ __forceinline__ void merge5u(ull& a0, ull& a1, ull& a2, ull& a3, ull& a4,
                                        ull b0, ull b1, ull b2, ull b3, ull b4) {
    ull m0 = umin64(a0, b0);
    ull m1 = umin64(umin64(a1, b1), umax64(a0, b0));
    ull m2 = umin64(umin64(a2, b2), umin64(umax64(a0, b1), umax64(a1, b0)));
    ull m3 = umin64(umin64(a3, b3),
                    umin64(umin64(umax64(a0, b2), umax64(a1, b1)), umax64(a2, b0)));
    ull m4 = umin64(umin64(a4, b4),
                    umin64(umin64(umax64(a0, b3), umax64(a1, b2)),
                           umin64(umax64(a2, b1), umax64(a3, b0))));
    a0 = m0; a1 = m1; a2 = m2; a3 = m3; a4 = m4;
}

__device__ __forceinline__ void insert5u(ull key, ull& k0, ull& k1, ull& k2, ull& k3, ull& k4) {
    if (key < k4) {
        k4 = key;
        ull t;
        if (k4 < k3) { t = k3; k3 = k4; k4 = t; }
        if (k3 < k2) { t = k2; k2 = k3; k3 = t; }
        if (k2 < k1) { t = k1; k1 = k2; k2 = t; }
        if (k1 < k0) { t = k0; k0 = k1; k1 = t; }
    }
}

#define BFLYU(kk0,kk1,kk2,kk3,kk4,WIDTH)                            \
    for (int mask_ = 1; mask_ < (WIDTH); mask_ <<= 1) {             \
        ull b0_ = __shfl_xor(kk0, mask_, 64);                       \
        ull b1_ = __shfl_xor(kk1, mask_, 64);                       \
        ull b2_ = __shfl_xor(kk2, mask_, 64);                       \
        ull b3_ = __shfl_xor(kk3, mask_, 64);                       \
        ull b4_ = __shfl_xor(kk4, mask_, 64);                       \
        merge5u(kk0, kk1, kk2, kk3, kk4, b0_, b1_, b2_, b3_, b4_);  \
    }

// ---------------------------------------------------------------------------
// One cooperative dispatch = R4's proven structure with the inter-kernel gap
// replaced by grid.sync().
// Phase A (all 32 blocks): copy X->out + per-block candidate filter into
//   per-block ws regions (ballot compaction, no atomics, counts[] written
//   unconditionally -> poison-safe).
// Phase B (block 0): 3 exact fixed-point iterations over the candidates,
//   then scatter v to missing cells (ordered after the copy by grid sync).
// Threshold proof (v0=0): r0 = global 5th-smallest observed |x|; r_loc
// (block slice 5th-smallest) >= r0. Iter-1 picks |x|<=r0 -> |v1|<=r0;
// d5(v1)<=2r0 -> iter-2 picks |x|<=3r0 -> |v2|<=3r0; d5(v2)<=4r0 -> iter-3
// picks |x|<=7r0. Keeping x^2 <= 64*r_loc^2 >= (8r0)^2 -> strict superset of
// everything selectable. Overflow/degenerate -> exact full-scan fallback.
// ---------------------------------------------------------------------------
__global__ void __launch_bounds__(TPB) knn_coop_kernel(
    const float* __restrict__ X, const int* __restrict__ miss_idx,
    const int* __restrict__ obs_idx, float* __restrict__ out,
    uint2* __restrict__ cand, int* __restrict__ counts,
    int n, int n_obs, int n_miss, int per, int percap)
{
    __shared__ ull   sku[NW * 5];
    __shared__ int   wcnt[NW];
    __shared__ float thr_sh, v_sh;
    __shared__ uint2 cs[CAPS];          // block 0 only (phase B)
    __shared__ int   bases[NBLK + 1];
    __shared__ int   bad_sh;

    const int tid  = threadIdx.x;
    const int b    = blockIdx.x;
    const int wid  = tid >> 6;
    const int lane = tid & 63;
    const int gtid = b * TPB + tid;
    const int gsz  = NBLK * TPB;
    const int n4   = n >> 2;

    // ===== Phase A1: coalesced copy X -> out =====
    for (int i = gtid; i < n4; i += gsz)
        reinterpret_cast<float4*>(out)[i] = reinterpret_cast<const float4*>(X)[i];
    for (int t = (n4 << 2) + gtid; t < n; t += gsz) out[t] = X[t];

    // ===== Phase A2: slice threshold (block-local 5th-smallest x^2) =====
    const int j0 = b * per;
    const int j1 = min(j0 + per, n_obs);

    int   pi[4]; float xv[4];
#pragma unroll
    for (int u = 0; u < 4; ++u) {
        int j = j0 + tid + u * TPB;
        pi[u] = (j < j1) ? obs_idx[j] : 0;
    }
#pragma unroll
    for (int u = 0; u < 4; ++u) xv[u] = X[pi[u]];

    {
        ull k0 = ~0ull, k1 = ~0ull, k2 = ~0ull, k3 = ~0ull, k4 = ~0ull;
#pragma unroll
        for (int u = 0; u < 4; ++u) {
            int j = j0 + tid + u * TPB;
            if (j < j1) {
                float x = xv[u];
                insert5u(((ull)__float_as_uint(x * x) << 32) | (unsigned)pi[u],
                         k0, k1, k2, k3, k4);
            }
        }
        BFLYU(k0, k1, k2, k3, k4, 64)
        if (lane == 0) {
            sku[wid * 5 + 0] = k0; sku[wid * 5 + 1] = k1; sku[wid * 5 + 2] = k2;
            sku[wid * 5 + 3] = k3; sku[wid * 5 + 4] = k4;
        }
        __syncthreads();
        if (wid == 0) {
            ull g0 = ~0ull, g1 = ~0ull, g2 = ~0ull, g3 = ~0ull, g4 = ~0ull;
            if (lane < NW) {
                g0 = sku[lane * 5 + 0]; g1 = sku[lane * 5 + 1]; g2 = sku[lane * 5 + 2];
                g3 = sku[lane * 5 + 3]; g4 = sku[lane * 5 + 4];
            }
            BFLYU(g0, g1, g2, g3, g4, NW)
            if (lane == 0) {
                float d5 = __uint_as_float((unsigned)(g4 >> 32));   // r_loc^2
                thr_sh = 64.0f * d5;   // (8*r_loc)^2; NaN/inf -> empty/all -> fallback path
            }
        }
        __syncthreads();
    }
    const float thr = thr_sh;

    // ===== Phase A3: order-preserving ballot compaction into ws region =====
    const ull lanemask_lt = (1ull << lane) - 1ull;
    int base = 0;
#pragma unroll
    for (int u = 0; u < 4; ++u) {
        int  j    = j0 + tid + u * TPB;
        bool keep = (j < j1) && (xv[u] * xv[u] <= thr);
        ull  mask = __ballot(keep);
        if (lane == 0) wcnt[wid] = (int)__popcll(mask);
        __syncthreads();
        int wbase = 0, utot = 0;
#pragma unroll
        for (int w = 0; w < NW; ++w) {
            if (w == wid) wbase = utot;
            utot += wcnt[w];
        }
        int pos = base + wbase + (int)__popcll(mask & lanemask_lt);
        if (keep && pos < percap)
            cand[b * percap + pos] = make_uint2(__float_as_uint(xv[u]), (unsigned)pi[u]);
        base += utot;
        __syncthreads();
    }
    if (tid == 0) counts[b] = base;     // may exceed percap -> solve falls back

    __threadfence();                    // device-scope visibility of cand/counts/out
    cg::this_grid().sync();

    // ===== Phase B: block 0 solves + scatters =====
    if (b != 0) return;

    if (tid == 0) {
        int C = 0, bad = 0;
        for (int r = 0; r < NBLK; ++r) {
            bases[r] = C;
            int c = counts[r];
            if (c > percap) bad = 1;
            C += c;
        }
        bases[NBLK] = C;
        bad_sh = bad || (C < 5) || (C > CAPS) || (percap <= 0);
    }
    __syncthreads();
    const int  C    = bases[NBLK];
    const bool fast = !bad_sh;

    if (fast) {
        for (int r = tid >> 4; r < NBLK; r += TPB / 16) {
            int bb = bases[r], cr = bases[r + 1] - bases[r];
            for (int e = tid & 15; e < cr; e += 16)
                cs[bb + e] = cand[r * percap + e];
        }
    }
    __syncthreads();

    float v = 0.0f;   // reference inits missing entries to 0
    for (int it = 0; it < 3; ++it) {
        ull q0 = ~0ull, q1 = ~0ull, q2 = ~0ull, q3 = ~0ull, q4 = ~0ull;
        if (fast) {
            for (int e = tid; e < C; e += TPB) {
                uint2 ce = cs[e];
                float x  = __uint_as_float(ce.x);
                float df = v - x;
                insert5u(((ull)__float_as_uint(df * df) << 32) | (ull)ce.y,
                         q0, q1, q2, q3, q4);
            }
        } else {
            // exact full-scan fallback (never expected on this data)
            for (int e = tid; e < n_obs; e += TPB) {
                int   p  = obs_idx[e];
                float x  = X[p];
                float df = v - x;
                insert5u(((ull)__float_as_uint(df * df) << 32) | (unsigned)p,
                         q0, q1, q2, q3, q4);
            }
        }
        BFLYU(q0, q1, q2, q3, q4, 64)
        if (lane == 0) {
            sku[wid * 5 + 0] = q0; sku[wid * 5 + 1] = q1; sku[wid * 5 + 2] = q2;
            sku[wid * 5 + 3] = q3; sku[wid * 5 + 4] = q4;
        }
        __syncthreads();
        if (wid == 0) {
            ull g0 = ~0ull, g1 = ~0ull, g2 = ~0ull, g3 = ~0ull, g4 = ~0ull;
            if (lane < NW) {
                g0 = sku[lane * 5 + 0]; g1 = sku[lane * 5 + 1]; g2 = sku[lane * 5 + 2];
                g3 = sku[lane * 5 + 3]; g4 = sku[lane * 5 + 4];
            }
            BFLYU(g0, g1, g2, g3, g4, NW)
            // winner values: direct X[p] loads (L1/L2-hot), 5 parallel lanes
            float x5 = 0.0f;
            if (lane < 5) {
                ull key = (lane == 0) ? g0 : (lane == 1) ? g1 : (lane == 2) ? g2
                         : (lane == 3) ? g3 : g4;
                if (key != ~0ull) x5 = X[(unsigned)(key & 0xFFFFFFFFull)];
            }
            float x0 = __shfl(x5, 0, 64), x1 = __shfl(x5, 1, 64), x2 = __shfl(x5, 2, 64),
                  x3 = __shfl(x5, 3, 64), x4v = __shfl(x5, 4, 64);
            if (lane == 0) {
                // ascending (dist, p) order == reference's sum order exactly
                float s = x0; s += x1; s += x2; s += x3; s += x4v;
                v_sh = s * 0.2f;
            }
        }
        __syncthreads();
        v = v_sh;
        __syncthreads();
    }

    // scatter v (ordered after all blocks' copies by the grid sync)
    for (int m = tid; m < n_miss; m += TPB) out[miss_idx[m]] = v;
}

// Minimal exact single-block fallback (only if ws is unusable).
__global__ void __launch_bounds__(1024) knn_exact_kernel(
    const float* __restrict__ X, const int* __restrict__ miss_idx,
    const int* __restrict__ obs_idx, float* __restrict__ out,
    int n, int n_obs, int n_miss)
{
    __shared__ ull   sku[(1024 / 64) * 5];
    __shared__ float v_sh;
    const int tid = threadIdx.x, wid = tid >> 6, lane = tid & 63;
    const int n4 = n >> 2;
    for (int i = tid; i < n4; i += 1024)
        reinterpret_cast<float4*>(out)[i] = reinterpret_cast<const float4*>(X)[i];
    for (int t = (n4 << 2) + tid; t < n; t += 1024) out[t] = X[t];

    float v = 0.0f;
    for (int it = 0; it < 3; ++it) {
        ull k0 = ~0ull, k1 = ~0ull, k2 = ~0ull, k3 = ~0ull, k4 = ~0ull;
        for (int e = tid; e < n_obs; e += 1024) {
            int p = obs_idx[e];
            float df = v - X[p];
            insert5u(((ull)__float_as_uint(df * df) << 32) | (unsigned)p, k0, k1, k2, k3, k4);
        }
        BFLYU(k0, k1, k2, k3, k4, 64)
        if (lane == 0) {
            sku[wid * 5 + 0] = k0; sku[wid * 5 + 1] = k1; sku[wid * 5 + 2] = k2;
            sku[wid * 5 + 3] = k3; sku[wid * 5 + 4] = k4;
        }
        __syncthreads();
        if (wid == 0) {
            ull g0 = ~0ull, g1 = ~0ull, g2 = ~0ull, g3 = ~0ull, g4 = ~0ull;
            if (lane < 16) {
                g0 = sku[lane * 5 + 0]; g1 = sku[lane * 5 + 1]; g2 = sku[lane * 5 + 2];
                g3 = sku[lane * 5 + 3]; g4 = sku[lane * 5 + 4];
            }
            BFLYU(g0, g1, g2, g3, g4, 16)
            float x5 = 0.0f;
            if (lane < 5) {
                ull key = (lane == 0) ? g0 : (lane == 1) ? g1 : (lane == 2) ? g2
                         : (lane == 3) ? g3 : g4;
                if (key != ~0ull) x5 = X[(unsigned)(key & 0xFFFFFFFFull)];
            }
            float x0 = __shfl(x5, 0, 64), x1 = __shfl(x5, 1, 64), x2 = __shfl(x5, 2, 64),
                  x3 = __shfl(x5, 3, 64), x4v = __shfl(x5, 4, 64);
            if (lane == 0) { float s = x0; s += x1; s += x2; s += x3; s += x4v; v_sh = s * 0.2f; }
        }
        __syncthreads();
        v = v_sh;
        __syncthreads();
    }
    for (int m = tid; m < n_miss; m += 1024) out[miss_idx[m]] = v;
}

extern "C" void kernel_launch(void* const* d_in, const int* in_sizes, int n_in,
                              void* d_out, int out_size, void* d_ws, size_t ws_size,
                              hipStream_t stream) {
    const float* X        = (const float*)d_in[0];
    const int*   miss_idx = (const int*)d_in[1];
    const int*   obs_idx  = (const int*)d_in[2];
    float*       out      = (float*)d_out;

    int n_miss = in_sizes[1];
    int n_obs  = in_sizes[2];
    int n      = out_size;
    int per    = (n_obs + NBLK - 1) / NBLK;

    size_t need = 256 + (size_t)NBLK * PERCAP * sizeof(uint2);
    if (ws_size < need) {
        // ws unusable for the candidate pipeline -> exact single-block path
        knn_exact_kernel<<<1, 1024, 0, stream>>>(X, miss_idx, obs_idx, out,
                                                 n, n_obs, n_miss);
        return;
    }

    int    percap = PERCAP;
    int*   counts = (int*)d_ws;
    uint2* cand   = (uint2*)((char*)d_ws + 256);

    void* args[] = {
        (void*)&X, (void*)&miss_idx, (void*)&obs_idx, (void*)&out,
        (void*)&cand, (void*)&counts,
        (void*)&n, (void*)&n_obs, (void*)&n_miss, (void*)&per, (void*)&percap
    };
    hipLaunchCooperativeKernel((const void*)knn_coop_kernel,
                               dim3(NBLK), dim3(TPB), args, 0, stream);
}

// Round 8
// 30.259 us; speedup vs baseline: 1.7447x; 1.7447x over previous
//
#include <hip/hip_runtime.h>
#include <math.h>

#define TPB_A  256        // prep threads/block
#define NBLK   32         // prep blocks
#define TPB_B  256        // solve threads (1 block)
#define PERCAP 256        // candidate slots per block region in ws
#define CAPS   2048       // solve candidate capacity (= CPL*64)
#define CPL    32         // candidates per lane in solve wave 0
#define NW_A   (TPB_A / 64)
#define NW_B   (TPB_B / 64)

typedef unsigned long long ull;

__device__ __forceinline__ ull umin64(ull a, ull b) { return a < b ? a : b; }
__device__ __forceinline__ ull umax64(ull a, ull b) { return a > b ? a : b; }

// Branchless order-statistic merge of two ascending 5-lists of 64-bit keys.
// Key = (dist_bits << 32) | p. obs_idx is sorted, so ordering/tie-break by
// cell index p is a monotone bijection of the reference's obs-enumeration
// index j -> exact jax.lax.top_k semantics (lower index wins ties).
__device__ __forceinline__ void merge5u(ull& a0, ull& a1, ull& a2, ull& a3, ull& a4,
                                        ull b0, ull b1, ull b2, ull b3, ull b4) {
    ull m0 = umin64(a0, b0);
    ull m1 = umin64(umin64(a1, b1), umax64(a0, b0));
    ull m2 = umin64(umin64(a2, b2), umin64(umax64(a0, b1), umax64(a1, b0)));
    ull m3 = umin64(umin64(a3, b3),
                    umin64(umin64(umax64(a0, b2), umax64(a1, b1)), umax64(a2, b0)));
    ull m4 = umin64(umin64(a4, b4),
                    umin64(umin64(umax64(a0, b3), umax64(a1, b2)),
                           umin64(umax64(a2, b1), umax64(a3, b0))));
    a0 = m0; a1 = m1; a2 = m2; a3 = m3; a4 = m4;
}

__device__ __forceinline__ void insert5u(ull key, ull& k0, ull& k1, ull& k2, ull& k3, ull& k4) {
    if (key < k4) {
        k4 = key;
        ull t;
        if (k4 < k3) { t = k3; k3 = k4; k4 = t; }
        if (k3 < k2) { t = k2; k2 = k3; k3 = t; }
        if (k2 < k1) { t = k1; k1 = k2; k2 = t; }
        if (k1 < k0) { t = k0; k0 = k1; k1 = t; }
    }
}

#define BFLYU(kk0,kk1,kk2,kk3,kk4,WIDTH)                            \
    for (int mask_ = 1; mask_ < (WIDTH); mask_ <<= 1) {             \
        ull b0_ = __shfl_xor(kk0, mask_, 64);                       \
        ull b1_ = __shfl_xor(kk1, mask_, 64);                       \
        ull b2_ = __shfl_xor(kk2, mask_, 64);                       \
        ull b3_ = __shfl_xor(kk3, mask_, 64);                       \
        ull b4_ = __shfl_xor(kk4, mask_, 64);                       \
        merge5u(kk0, kk1, kk2, kk3, kk4, b0_, b1_, b2_, b3_, b4_);  \
    }

// ---------------------------------------------------------------------------
// Kernel A (32 blocks): copy X->out; slice top-5 by (x^2,p) -> ws keys
// (= this slice's contribution to iteration 1 AND the threshold r_loc^2);
// single-barrier prefix compaction of candidates (x^2 <= 64*r_loc^2) into
// the block's ws region. counts[b]/keys written unconditionally (poison-safe).
// Threshold proof (v0=0): r0 = global 5th-smallest observed |x| <= r_loc.
// iter1 picks |x|<=r0 -> |v1|<=r0; d5(v1)<=2r0 -> iter2 picks |x|<=3r0 ->
// |v2|<=3r0; d5(v2)<=4r0 -> iter3 picks |x|<=7r0 < 8r0 <= 8r_loc. So the
// kept set is a strict superset of everything selectable.
// ---------------------------------------------------------------------------
__global__ void __launch_bounds__(TPB_A) knn_prep_kernel(
    const float* __restrict__ X, const int* __restrict__ obs_idx,
    float* __restrict__ out, int* __restrict__ counts,
    uint4* __restrict__ keys, uint2* __restrict__ cand,
    int n, int n_obs, int per, int percap)
{
    __shared__ ull      sku[NW_A * 5];
    __shared__ ull      gk[5];
    __shared__ unsigned wp5[5];
    __shared__ float    vals5[5];
    __shared__ float    thr_sh;
    __shared__ int      wsum[NW_A];

    const int tid  = threadIdx.x;
    const int b    = blockIdx.x;
    const int wid  = tid >> 6;
    const int lane = tid & 63;
    const int gtid = b * TPB_A + tid;
    const int gsz  = NBLK * TPB_A;
    const int n4   = n >> 2;

    // ---- copy X -> out, grid-strided float4 ----
    for (int i = gtid; i < n4; i += gsz)
        reinterpret_cast<float4*>(out)[i] = reinterpret_cast<const float4*>(X)[i];
    for (int t = (n4 << 2) + gtid; t < n; t += gsz) out[t] = X[t];

    // ---- gather slice ----
    const int j0 = b * per;
    const int j1 = min(j0 + per, n_obs);
    int   pi[4]; float xv[4];
#pragma unroll
    for (int u = 0; u < 4; ++u) {
        int j = j0 + tid + u * TPB_A;
        pi[u] = (j < j1) ? obs_idx[j] : 0;
    }
#pragma unroll
    for (int u = 0; u < 4; ++u) xv[u] = X[pi[u]];

    // ---- slice top-5 by (x^2, p) == slice's iter-1 contribution ----
    ull k0 = ~0ull, k1 = ~0ull, k2 = ~0ull, k3 = ~0ull, k4 = ~0ull;
#pragma unroll
    for (int u = 0; u < 4; ++u) {
        int j = j0 + tid + u * TPB_A;
        if (j < j1) {
            float x = xv[u];
            insert5u(((ull)__float_as_uint(x * x) << 32) | (unsigned)pi[u],
                     k0, k1, k2, k3, k4);
        }
    }
    BFLYU(k0, k1, k2, k3, k4, 64)
    if (lane == 0) {
        sku[wid * 5 + 0] = k0; sku[wid * 5 + 1] = k1; sku[wid * 5 + 2] = k2;
        sku[wid * 5 + 3] = k3; sku[wid * 5 + 4] = k4;
    }
    if (tid < 5) vals5[tid] = 0.0f;
    __syncthreads();
    if (wid == 0) {
        ull g0 = ~0ull, g1 = ~0ull, g2 = ~0ull, g3 = ~0ull, g4 = ~0ull;
        if (lane < NW_A) {
            g0 = sku[lane * 5 + 0]; g1 = sku[lane * 5 + 1]; g2 = sku[lane * 5 + 2];
            g3 = sku[lane * 5 + 3]; g4 = sku[lane * 5 + 4];
        }
        BFLYU(g0, g1, g2, g3, g4, NW_A)
        if (lane == 0) {
            gk[0] = g0; gk[1] = g1; gk[2] = g2; gk[3] = g3; gk[4] = g4;
            wp5[0] = (unsigned)g0; wp5[1] = (unsigned)g1; wp5[2] = (unsigned)g2;
            wp5[3] = (unsigned)g3; wp5[4] = (unsigned)g4;
            float d5 = __uint_as_float((unsigned)(g4 >> 32));  // r_loc^2
            thr_sh = 64.0f * d5;   // (8*r_loc)^2; NaN -> keeps none -> fallback
        }
    }
    __syncthreads();
    const float thr = thr_sh;

    // ---- match winner values (p unique -> exactly one writer per slot) ----
#pragma unroll
    for (int u = 0; u < 4; ++u) {
        int j = j0 + tid + u * TPB_A;
        if (j < j1) {
#pragma unroll
            for (int i = 0; i < 5; ++i)
                if ((unsigned)pi[u] == wp5[i]) vals5[i] = xv[u];
        }
    }

    // ---- single-barrier prefix compaction (slot order irrelevant: p carried) ----
    bool keep[4];
    int  tcnt = 0;
#pragma unroll
    for (int u = 0; u < 4; ++u) {
        int j = j0 + tid + u * TPB_A;
        keep[u] = (j < j1) && (xv[u] * xv[u] <= thr);
        tcnt += keep[u] ? 1 : 0;
    }
    int incl = tcnt;
    for (int d = 1; d < 64; d <<= 1) {
        int o = __shfl_up(incl, d, 64);
        if (lane >= d) incl += o;
    }
    if (lane == 63) wsum[wid] = incl;
    __syncthreads();

    // keys write (vals5 final after the barrier above)
    if (tid < 5) {
        ull g = gk[tid];
        keys[b * 5 + tid] = make_uint4((unsigned)(g & 0xFFFFFFFFull),
                                       (unsigned)(g >> 32),
                                       __float_as_uint(vals5[tid]), 0u);
    }
    int wexcl = 0, btotal = 0;
#pragma unroll
    for (int w = 0; w < NW_A; ++w) {
        if (w == wid) wexcl = btotal;
        btotal += wsum[w];
    }
    int pos = wexcl + incl - tcnt;
#pragma unroll
    for (int u = 0; u < 4; ++u) {
        if (keep[u]) {
            if (pos < percap)
                cand[b * percap + pos] = make_uint2(__float_as_uint(xv[u]), (unsigned)pi[u]);
            ++pos;
        }
    }
    if (tid == 0) counts[b] = btotal;   // may exceed percap -> solve falls back
}

// ---------------------------------------------------------------------------
// Kernel B (1 block, wave-0 solver): iteration 1 from the 160 prep keys
// (exact global top-5 merge), iterations 2-3 in-register over the staged
// candidates. All threads stage + scatter.
// ---------------------------------------------------------------------------
__global__ void __launch_bounds__(TPB_B) knn_solve_kernel(
    const float* __restrict__ X, const int* __restrict__ miss_idx,
    const int* __restrict__ obs_idx, float* __restrict__ out,
    const int* __restrict__ counts, const uint4* __restrict__ keys,
    const uint2* __restrict__ cand, int n_obs, int n_miss, int percap)
{
    __shared__ uint2 cs[CAPS];
    __shared__ int   bases[NBLK + 1];
    __shared__ int   bad_sh;
    __shared__ float v_sh;
    __shared__ ull   sku[NW_B * 5];     // fallback only

    const int tid  = threadIdx.x;
    const int wid  = tid >> 6;
    const int lane = tid & 63;

    // ---- bases + overflow check (wave 0) ----
    if (wid == 0) {
        int c = (lane < NBLK) ? counts[lane] : 0;
        ull bb = __ballot((lane < NBLK) && (c > percap || c < 0));
        int incl = c;
        for (int d = 1; d < NBLK; d <<= 1) {
            int o = __shfl_up(incl, d, 64);
            if (lane >= d) incl += o;
        }
        if (lane < NBLK) bases[lane] = incl - c;
        if (lane == NBLK - 1) bases[NBLK] = incl;
        if (lane == 0) bad_sh = (bb != 0ull) || (percap <= 0);
    }
    __syncthreads();
    const int  C    = bases[NBLK];
    const bool fast = !bad_sh && (C >= 5) && (C <= CAPS);

    // ---- stage candidates: 8 threads per region, all waves ----
    if (fast) {
        const int r   = tid >> 3;       // 0..31
        const int off = tid & 7;
        const int bb  = bases[r];
        const int cr  = bases[r + 1] - bb;
        for (int e = off; e < cr; e += 8)
            cs[bb + e] = cand[r * percap + e];
    }
    __syncthreads();

    float v = 0.0f;   // reference inits missing entries to 0

    if (fast) {
        if (wid == 0) {
            // ---- iteration 1: merge 160 slice-top-5 (key,val) tuples ----
            ull      kk[3]; float kv[3]; unsigned kp[3];
            ull q0 = ~0ull, q1 = ~0ull, q2 = ~0ull, q3 = ~0ull, q4 = ~0ull;
#pragma unroll
            for (int t = 0; t < 3; ++t) {
                int e = lane + t * 64;
                kk[t] = ~0ull; kv[t] = 0.0f; kp[t] = 0xFFFFFFFFu;
                if (e < NBLK * 5) {
                    uint4 u4 = keys[e];
                    kk[t] = ((ull)u4.y << 32) | u4.x;
                    kv[t] = __uint_as_float(u4.z);
                    kp[t] = u4.x;
                    insert5u(kk[t], q0, q1, q2, q3, q4);
                }
            }
            BFLYU(q0, q1, q2, q3, q4, 64)
            // values via register match + ballot/ffs/shfl (sentinels can't win: C>=5)
            float xw[5];
            ull   wcur[5] = {q0, q1, q2, q3, q4};
#pragma unroll
            for (int i = 0; i < 5; ++i) {
                unsigned wp = (unsigned)(wcur[i] & 0xFFFFFFFFull);
                bool have = false; float xval = 0.0f;
#pragma unroll
                for (int t = 0; t < 3; ++t)
                    if (kk[t] != ~0ull && kp[t] == wp) { have = true; xval = kv[t]; }
                ull bal = __ballot(have);
                int src = (int)__ffsll(bal) - 1;
                xw[i] = __shfl(xval, src, 64);
            }
            // ascending (dist, p) order == reference sum order
            float s = xw[0]; s += xw[1]; s += xw[2]; s += xw[3]; s += xw[4];
            v = s * 0.2f;

            // ---- load candidates into registers (static-indexed) ----
            float cx[CPL]; unsigned cp[CPL];
#pragma unroll
            for (int t = 0; t < CPL; ++t) {
                int e = lane + t * 64;
                if (e < C) { uint2 ce = cs[e]; cx[t] = __uint_as_float(ce.x); cp[t] = ce.y; }
                else       { cx[t] = 0.0f; cp[t] = 0xFFFFFFFFu; }
            }

            // ---- iterations 2 and 3, pure in-register ----
#pragma unroll
            for (int it = 0; it < 2; ++it) {
                ull r0 = ~0ull, r1 = ~0ull, r2 = ~0ull, r3 = ~0ull, r4 = ~0ull;
#pragma unroll
                for (int t = 0; t < CPL; ++t) {
                    int e = lane + t * 64;
                    if (e < C) {
                        float df = v - cx[t];
                        insert5u(((ull)__float_as_uint(df * df) << 32) | (ull)cp[t],
                                 r0, r1, r2, r3, r4);
                    }
                }
                BFLYU(r0, r1, r2, r3, r4, 64)
                ull wc[5] = {r0, r1, r2, r3, r4};
#pragma unroll
                for (int i = 0; i < 5; ++i) {
                    unsigned wp = (unsigned)(wc[i] & 0xFFFFFFFFull);
                    bool have = false; float xval = 0.0f;
#pragma unroll
                    for (int t = 0; t < CPL; ++t)
                        if (cp[t] == wp) { have = true; xval = cx[t]; }
                    ull bal = __ballot(have);
                    int src = (int)__ffsll(bal) - 1;
                    xw[i] = __shfl(xval, src, 64);
                }
                float s2 = xw[0]; s2 += xw[1]; s2 += xw[2]; s2 += xw[3]; s2 += xw[4];
                v = s2 * 0.2f;
            }
            if (lane == 0) v_sh = v;
        }
        __syncthreads();
        v = v_sh;
    } else {
        // ---- exact full-scan fallback (all waves, never expected) ----
        for (int it = 0; it < 3; ++it) {
            ull q0 = ~0ull, q1 = ~0ull, q2 = ~0ull, q3 = ~0ull, q4 = ~0ull;
            for (int e = tid; e < n_obs; e += TPB_B) {
                int   p  = obs_idx[e];
                float df = v - X[p];
                insert5u(((ull)__float_as_uint(df * df) << 32) | (unsigned)p,
                         q0, q1, q2, q3, q4);
            }
            BFLYU(q0, q1, q2, q3, q4, 64)
            if (lane == 0) {
                sku[wid * 5 + 0] = q0; sku[wid * 5 + 1] = q1; sku[wid * 5 + 2] = q2;
                sku[wid * 5 + 3] = q3; sku[wid * 5 + 4] = q4;
            }
            __syncthreads();
            if (wid == 0) {
                ull g0 = ~0ull, g1 = ~0ull, g2 = ~0ull, g3 = ~0ull, g4 = ~0ull;
                if (lane < NW_B) {
                    g0 = sku[lane * 5 + 0]; g1 = sku[lane * 5 + 1]; g2 = sku[lane * 5 + 2];
                    g3 = sku[lane * 5 + 3]; g4 = sku[lane * 5 + 4];
                }
                BFLYU(g0, g1, g2, g3, g4, NW_B)
                float x5 = 0.0f;
                if (lane < 5) {
                    ull key = (lane == 0) ? g0 : (lane == 1) ? g1 : (lane == 2) ? g2
                             : (lane == 3) ? g3 : g4;
                    if (key != ~0ull) x5 = X[(unsigned)(key & 0xFFFFFFFFull)];
                }
                float x0 = __shfl(x5, 0, 64), x1 = __shfl(x5, 1, 64), x2 = __shfl(x5, 2, 64),
                      x3 = __shfl(x5, 3, 64), x4v = __shfl(x5, 4, 64);
                if (lane == 0) {
                    float s = x0; s += x1; s += x2; s += x3; s += x4v;
                    v_sh = s * 0.2f;
                }
            }
            __syncthreads();
            v = v_sh;
            __syncthreads();
        }
    }

    // ---- scatter (ordered after prep's copy by node order) ----
    for (int m = tid; m < n_miss; m += TPB_B) out[miss_idx[m]] = v;
}

// Exact single-block fallback if ws is unusable or slice scheme doesn't fit.
__global__ void __launch_bounds__(1024) knn_exact_kernel(
    const float* __restrict__ X, const int* __restrict__ miss_idx,
    const int* __restrict__ obs_idx, float* __restrict__ out,
    int n, int n_obs, int n_miss)
{
    __shared__ ull   sku[(1024 / 64) * 5];
    __shared__ float v_sh;
    const int tid = threadIdx.x, wid = tid >> 6, lane = tid & 63;
    const int n4 = n >> 2;
    for (int i = tid; i < n4; i += 1024)
        reinterpret_cast<float4*>(out)[i] = reinterpret_cast<const float4*>(X)[i];
    for (int t = (n4 << 2) + tid; t < n; t += 1024) out[t] = X[t];

    float v = 0.0f;
    for (int it = 0; it < 3; ++it) {
        ull k0 = ~0ull, k1 = ~0ull, k2 = ~0ull, k3 = ~0ull, k4 = ~0ull;
        for (int e = tid; e < n_obs; e += 1024) {
            int p = obs_idx[e];
            float df = v - X[p];
            insert5u(((ull)__float_as_uint(df * df) << 32) | (unsigned)p, k0, k1, k2, k3, k4);
        }
        BFLYU(k0, k1, k2, k3, k4, 64)
        if (lane == 0) {
            sku[wid * 5 + 0] = k0; sku[wid * 5 + 1] = k1; sku[wid * 5 + 2] = k2;
            sku[wid * 5 + 3] = k3; sku[wid * 5 + 4] = k4;
        }
        __syncthreads();
        if (wid == 0) {
            ull g0 = ~0ull, g1 = ~0ull, g2 = ~0ull, g3 = ~0ull, g4 = ~0ull;
            if (lane < 16) {
                g0 = sku[lane * 5 + 0]; g1 = sku[lane * 5 + 1]; g2 = sku[lane * 5 + 2];
                g3 = sku[lane * 5 + 3]; g4 = sku[lane * 5 + 4];
            }
            BFLYU(g0, g1, g2, g3, g4, 16)
            float x5 = 0.0f;
            if (lane < 5) {
                ull key = (lane == 0) ? g0 : (lane == 1) ? g1 : (lane == 2) ? g2
                         : (lane == 3) ? g3 : g4;
                if (key != ~0ull) x5 = X[(unsigned)(key & 0xFFFFFFFFull)];
            }
            float x0 = __shfl(x5, 0, 64), x1 = __shfl(x5, 1, 64), x2 = __shfl(x5, 2, 64),
                  x3 = __shfl(x5, 3, 64), x4v = __shfl(x5, 4, 64);
            if (lane == 0) { float s = x0; s += x1; s += x2; s += x3; s += x4v; v_sh = s * 0.2f; }
        }
        __syncthreads();
        v = v_sh;
        __syncthreads();
    }
    for (int m = tid; m < n_miss; m += 1024) out[miss_idx[m]] = v;
}

extern "C" void kernel_launch(void* const* d_in, const int* in_sizes, int n_in,
                              void* d_out, int out_size, void* d_ws, size_t ws_size,
                              hipStream_t stream) {
    const float* X        = (const float*)d_in[0];
    const int*   miss_idx = (const int*)d_in[1];
    const int*   obs_idx  = (const int*)d_in[2];
    float*       out      = (float*)d_out;

    int n_miss = in_sizes[1];
    int n_obs  = in_sizes[2];
    int n      = out_size;
    int per    = (n_obs + NBLK - 1) / NBLK;

    // ws layout: counts[32] @0 | keys[160] uint4 @256 | cand regions @4096
    size_t need = 4096 + (size_t)NBLK * PERCAP * sizeof(uint2);
    if (ws_size < need || per > 4 * TPB_A) {
        knn_exact_kernel<<<1, 1024, 0, stream>>>(X, miss_idx, obs_idx, out,
                                                 n, n_obs, n_miss);
        return;
    }

    int    percap = PERCAP;
    int*   counts = (int*)d_ws;
    uint4* keys   = (uint4*)((char*)d_ws + 256);
    uint2* cand   = (uint2*)((char*)d_ws + 4096);

    knn_prep_kernel<<<NBLK, TPB_A, 0, stream>>>(X, obs_idx, out, counts, keys, cand,
                                                n, n_obs, per, percap);
    knn_solve_kernel<<<1, TPB_B, 0, stream>>>(X, miss_idx, obs_idx, out,
                                              counts, keys, cand,
                                              n_obs, n_miss, percap);
}